// Round 9
// baseline (918.344 us; speedup 1.0000x reference)
//
#include <hip/hip_runtime.h>
#include <math.h>

// Problem constants (from reference)
#define NROWS 18432
#define IN_DIM 1024
#define HID_DIM 4096
#define OUT_DIM 4096
#define NTN 16   // 4096/256 column tiles (both layers)

typedef __attribute__((ext_vector_type(8))) short bf16x8;
typedef __attribute__((ext_vector_type(4))) float f32x4;

typedef const __attribute__((address_space(1))) char gchar;
typedef __attribute__((address_space(3))) char lchar;

__device__ __forceinline__ unsigned short f2bf(float f) {
    union { float f; unsigned u; } v; v.f = f;
    unsigned r = v.u + 0x7fffu + ((v.u >> 16) & 1u);  // RNE
    return (unsigned short)(r >> 16);
}

__device__ __forceinline__ f32x4 MFMA16(bf16x8 a, bf16x8 b, f32x4 c) {
    return __builtin_amdgcn_mfma_f32_16x16x32_bf16(a, b, c, 0, 0, 0);
}

// ---------------- conversion kernels ----------------

__global__ void cvt_f32_bf16_k(const float4* __restrict__ in, uint4* __restrict__ out, int nvec) {
    int i = blockIdx.x * blockDim.x + threadIdx.x;
    if (i >= nvec) return;
    float4 a = in[2 * i], b = in[2 * i + 1];
    union { unsigned short s[8]; uint4 v; } o;
    o.s[0] = f2bf(a.x); o.s[1] = f2bf(a.y); o.s[2] = f2bf(a.z); o.s[3] = f2bf(a.w);
    o.s[4] = f2bf(b.x); o.s[5] = f2bf(b.y); o.s[6] = f2bf(b.z); o.s[7] = f2bf(b.w);
    out[i] = o.v;
}

// int8 values harness-materialized as int32; exact in bf16
__global__ void cvt_i32_bf16_k(const int4* __restrict__ in, uint4* __restrict__ out, int nvec) {
    int i = blockIdx.x * blockDim.x + threadIdx.x;
    if (i >= nvec) return;
    int4 a = in[2 * i], b = in[2 * i + 1];
    union { unsigned short s[8]; uint4 v; } o;
    o.s[0] = f2bf((float)a.x); o.s[1] = f2bf((float)a.y);
    o.s[2] = f2bf((float)a.z); o.s[3] = f2bf((float)a.w);
    o.s[4] = f2bf((float)b.x); o.s[5] = f2bf((float)b.y);
    o.s[6] = f2bf((float)b.z); o.s[7] = f2bf((float)b.w);
    out[i] = o.v;
}

// ---- 256x256 GEMM, BK=32, triple-buffered LDS, ANTI-PHASED wave halves ----
// 8 waves (2M x 4N), per-wave 128x64 out. Each K32-tile splits into self-contained halves:
//   H0: {read af(4),bl(2) -> 8 MFMA af*bl}   H1: {read ah(4),bh(2) -> 8 MFMA ah*bh}
// then a cross block (16 MFMA af*bh + ah*bl, operands already in regs).
// Each SIMD hosts one wm=0 and one wm=1 wave; wm=0 runs H0->H1, wm=1 runs H1->H0, so at any
// instant one wave of the SIMD pair is in an MFMA cluster while the other is in its read
// cluster: LDS pipe || matrix pipe (the lockstep read-window/MFMA-window alternation capped
// rounds 4-8 at 45-48% MfmaUtil). setprio(1) around MFMA clusters arbitrates (T5: role split
// now exists). Zero extra registers vs round 8 (the reg-prefetch alternative would exceed the
// 256/wave budget at 2 waves/SIMD -> round-7 spill disaster).
// Ledger (unchanged, verified rounds 4/8): staging 2 tiles ahead, triple buffer;
// at iter t top outstanding = {t:4, t+1:4} -> vmcnt(4) drains tile t; tail vmcnt(0).
// WAR: STAGE(t+2) hits buf(t-1), whose reads retired before MFMA(t-1) < barrier(t).
// T2 swizzle (64-B rows): byte ^= ((row>>1)&3)<<4 on STAGE source + reads (rule 21).
// EPI==0: bf16 gelu(acc*sc+bi); EPI==1: f32 acc*sc+bi. Output row-stride hardcoded 4096.
template<int EPI>
__global__ __launch_bounds__(512, 2)
void gemmap(const unsigned short* __restrict__ A, const unsigned short* __restrict__ B,
            const float* __restrict__ scale, const float* __restrict__ bias,
            void* __restrict__ Cout, int K) {
    extern __shared__ __align__(16) char sm[];   // 98304 bytes dynamic (3 x 32KB)

    const int tid  = threadIdx.x;
    const int lane = tid & 63;
    const int wid  = tid >> 6;
    const int wm   = wid >> 2, wn = wid & 3;

    // T1: bijective XCD swizzle (m204)
    const int nwg  = gridDim.x;
    const int q    = nwg >> 3, r = nwg & 7;
    const int xcd  = blockIdx.x & 7, bidx = blockIdx.x >> 3;
    const int swz  = xcd * q + (xcd < r ? xcd : r) + bidx;
    const int tm   = swz / NTN, tn = swz % NTN;

    const size_t rowbytes = (size_t)K * 2;
    const char* Ag = (const char*)A + (size_t)tm * 256 * rowbytes;
    const char* Bg = (const char*)B + (size_t)tn * 256 * rowbytes;

    const int l16 = lane & 15;
    const int cg  = (lane >> 4) << 4;   // 16-B col slot within 64-B row

    f32x4  acc[8][4] = {};
    bf16x8 af[4], ah[4], bl[2], bh[2];

    const int NT = K >> 5;

#define STAGE(GB, LB, UNIT, KTB) { \
    const int po_ = ((UNIT) << 13) + (tid << 4); \
    const int r_  = po_ >> 6; \
    const int b_  = (po_ & 63) ^ (((r_ >> 1) & 3) << 4); \
    __builtin_amdgcn_global_load_lds( \
        (gchar*)((GB) + (size_t)r_ * rowbytes + (KTB) + (size_t)b_), \
        (lchar*)((LB) + po_), 16, 0, 0); \
}

#define RDA(BUF, ROW) ((BUF) + ((ROW) << 6) + (cg ^ ((((ROW) >> 1) & 3) << 4)))

#define SFENCE __builtin_amdgcn_sched_barrier(0)
#define WAITV4 { SFENCE; asm volatile("s_waitcnt vmcnt(4)"); SFENCE; }
#define WAITV0 { SFENCE; asm volatile("s_waitcnt vmcnt(0)"); SFENCE; }
#define BARR   { SFENCE; __builtin_amdgcn_s_barrier(); SFENCE; }

// half-read + half-MFMA clusters
#define RH0 { _Pragma("unroll") for (int mm = 0; mm < 4; ++mm) \
                  af[mm] = *(const bf16x8*)RDA(Ab, ab + mm * 16); \
              _Pragma("unroll") for (int nn = 0; nn < 2; ++nn) \
                  bl[nn] = *(const bf16x8*)RDA(Bb, bb + nn * 16); }
#define RH1 { _Pragma("unroll") for (int mm = 0; mm < 4; ++mm) \
                  ah[mm] = *(const bf16x8*)RDA(Ab, 128 + ab + mm * 16); \
              _Pragma("unroll") for (int nn = 0; nn < 2; ++nn) \
                  bh[nn] = *(const bf16x8*)RDA(Bb, 128 + bb + nn * 16); }
#define M_A { __builtin_amdgcn_s_setprio(1); \
              _Pragma("unroll") for (int mm = 0; mm < 4; ++mm) \
                  _Pragma("unroll") for (int nn = 0; nn < 2; ++nn) \
                      acc[mm][nn] = MFMA16(af[mm], bl[nn], acc[mm][nn]); \
              __builtin_amdgcn_s_setprio(0); }
#define M_B { __builtin_amdgcn_s_setprio(1); \
              _Pragma("unroll") for (int mm = 0; mm < 4; ++mm) \
                  _Pragma("unroll") for (int nn = 0; nn < 2; ++nn) \
                      acc[4 + mm][2 + nn] = MFMA16(ah[mm], bh[nn], acc[4 + mm][2 + nn]); \
              __builtin_amdgcn_s_setprio(0); }
#define M_X { __builtin_amdgcn_s_setprio(1); \
              _Pragma("unroll") for (int mm = 0; mm < 4; ++mm) \
                  _Pragma("unroll") for (int nn = 0; nn < 2; ++nn) { \
                      acc[mm][2 + nn] = MFMA16(af[mm], bh[nn], acc[mm][2 + nn]); \
                      acc[4 + mm][nn] = MFMA16(ah[mm], bl[nn], acc[4 + mm][nn]); } \
              __builtin_amdgcn_s_setprio(0); }

    // prologue: stage tile 0 -> buf0, tile 1 -> buf1 (8 units outstanding)
    {
        char* b0 = sm;
        STAGE(Ag, b0,         0, (size_t)0); STAGE(Ag, b0,         1, (size_t)0);
        STAGE(Bg, b0 + 16384, 0, (size_t)0); STAGE(Bg, b0 + 16384, 1, (size_t)0);
        char* b1 = sm + 32768;
        STAGE(Ag, b1,         0, (size_t)64); STAGE(Ag, b1,         1, (size_t)64);
        STAGE(Bg, b1 + 16384, 0, (size_t)64); STAGE(Bg, b1 + 16384, 1, (size_t)64);
    }

    for (int t = 0; t < NT; ++t) {
        if (t < NT - 1) { WAITV4; }   // tile t landed (only t+1's 4 units newer)
        else            { WAITV0; }   // tail
        BARR;                          // collective: tile t fully in LDS

        char* Ab = sm + 32768 * (t % 3);
        char* Bb = Ab + 16384;

        // stage tile t+2 into buf[(t+2)%3] (WAR safe past the barrier)
        if (t + 2 < NT) {
            char* Sb = sm + 32768 * ((t + 2) % 3);
            const size_t ktb = ((size_t)(t + 2)) << 6;
            STAGE(Ag, Sb,         0, ktb); STAGE(Ag, Sb,         1, ktb);
            STAGE(Bg, Sb + 16384, 0, ktb); STAGE(Bg, Sb + 16384, 1, ktb);
        }

        const int ab = (wm << 6) + l16;
        const int bb = (wn << 5) + l16;

        if (wm == 0) { RH0; M_A; RH1; M_B; }   // anti-phased halves across the
        else         { RH1; M_B; RH0; M_A; }   // SIMD's wave pair (wm0 + wm1)
        M_X;                                    // cross terms, operands in regs
    }
#undef STAGE
#undef RDA
#undef SFENCE
#undef WAITV4
#undef WAITV0
#undef BARR
#undef RH0
#undef RH1
#undef M_A
#undef M_B
#undef M_X

    // epilogue: C/D frag layout col=lane&15, row=(lane>>4)*4+r  [m89/m91]
    const int rg = (lane >> 4) << 2;
    #pragma unroll
    for (int j = 0; j < 4; ++j) {
        const int col = tn * 256 + ((j >> 1) << 7) + (wn << 5) + ((j & 1) << 4) + l16;
        const float sc = scale[col];
        const float bi = bias[col];
        #pragma unroll
        for (int m = 0; m < 8; ++m) {
            const int row0 = tm * 256 + ((m >> 2) << 7) + (wm << 6) + ((m & 3) << 4) + rg;
            #pragma unroll
            for (int rr = 0; rr < 4; ++rr) {
                float v = acc[m][j][rr] * sc + bi;
                if (EPI == 0) {
                    float g = 0.5f * v * (1.0f + erff(v * 0.70710678118654752f));
                    ((unsigned short*)Cout)[(size_t)(row0 + rr) * 4096 + col] = f2bf(g);
                } else {
                    ((float*)Cout)[(size_t)(row0 + rr) * 4096 + col] = v;
                }
            }
        }
    }
}

extern "C" void kernel_launch(void* const* d_in, const int* in_sizes, int n_in,
                              void* d_out, int out_size, void* d_ws, size_t ws_size,
                              hipStream_t stream) {
    const float* x   = (const float*)d_in[0];
    const int*   w1q = (const int*)d_in[1];
    const float* s1  = (const float*)d_in[2];
    const float* b1  = (const float*)d_in[3];
    const int*   w2q = (const int*)d_in[4];
    const float* s2  = (const float*)d_in[5];
    const float* b2  = (const float*)d_in[6];
    float*       out = (float*)d_out;

    // allow 96 KiB dynamic LDS (idempotent, not a stream op)
    hipFuncSetAttribute((const void*)gemmap<0>, hipFuncAttributeMaxDynamicSharedMemorySize, 98304);
    hipFuncSetAttribute((const void*)gemmap<1>, hipFuncAttributeMaxDynamicSharedMemorySize, 98304);

    char* ws = (char*)d_ws;
    const size_t XBF  = (size_t)NROWS   * IN_DIM  * 2;
    const size_t W1BF = (size_t)HID_DIM * IN_DIM  * 2;
    const size_t W2BF = (size_t)OUT_DIM * HID_DIM * 2;
    const size_t FIXED = XBF + W1BF + W2BF;

    unsigned short* xbf  = (unsigned short*)ws;
    unsigned short* w1bf = (unsigned short*)(ws + XBF);
    unsigned short* w2bf = (unsigned short*)(ws + XBF + W1BF);
    unsigned short* hbuf = (unsigned short*)(ws + FIXED);

    {
        int nvx = NROWS * IN_DIM / 8;
        cvt_f32_bf16_k<<<(nvx + 255) / 256, 256, 0, stream>>>((const float4*)x, (uint4*)xbf, nvx);
        int nv1 = HID_DIM * IN_DIM / 8;
        cvt_i32_bf16_k<<<(nv1 + 255) / 256, 256, 0, stream>>>((const int4*)w1q, (uint4*)w1bf, nv1);
        int nv2 = OUT_DIM * HID_DIM / 8;
        cvt_i32_bf16_k<<<(nv2 + 255) / 256, 256, 0, stream>>>((const int4*)w2q, (uint4*)w2bf, nv2);
    }

    // chunk M (multiples of 256) so h fits in remaining workspace
    size_t avail = (ws_size > FIXED) ? (ws_size - FIXED) : 0;
    long rp = (long)(avail / ((size_t)HID_DIM * 2));
    rp = (rp / 256) * 256;
    if (rp > NROWS) rp = NROWS;
    if (rp < 256)   rp = 256;

    for (int r0 = 0; r0 < NROWS; r0 += (int)rp) {
        int rows = (int)(((long)(NROWS - r0) < rp) ? (NROWS - r0) : rp);
        dim3 g(NTN * (rows / 256));
        gemmap<0><<<g, 512, 98304, stream>>>(xbf + (size_t)r0 * IN_DIM, w1bf, s1, b1,
                                             (void*)hbuf, IN_DIM);
        gemmap<1><<<g, 512, 98304, stream>>>(hbuf, w2bf, s2, b2,
                                             (void*)(out + (size_t)r0 * OUT_DIM), HID_DIM);
    }
    (void)in_sizes; (void)n_in; (void)out_size;
}

// Round 10
// 825.951 us; speedup vs baseline: 1.1119x; 1.1119x over previous
//
#include <hip/hip_runtime.h>
#include <math.h>

// Problem constants (from reference)
#define NROWS 18432
#define IN_DIM 1024
#define HID_DIM 4096
#define OUT_DIM 4096
#define NTN 16   // 4096/256 column tiles (both layers)

typedef __attribute__((ext_vector_type(8))) short bf16x8;
typedef __attribute__((ext_vector_type(4))) float f32x4;

typedef const __attribute__((address_space(1))) char gchar;
typedef __attribute__((address_space(3))) char lchar;

__device__ __forceinline__ unsigned short f2bf(float f) {
    union { float f; unsigned u; } v; v.f = f;
    unsigned r = v.u + 0x7fffu + ((v.u >> 16) & 1u);  // RNE
    return (unsigned short)(r >> 16);
}

__device__ __forceinline__ f32x4 MFMA16(bf16x8 a, bf16x8 b, f32x4 c) {
    return __builtin_amdgcn_mfma_f32_16x16x32_bf16(a, b, c, 0, 0, 0);
}

// ---------------- conversion kernels ----------------

__global__ void cvt_f32_bf16_k(const float4* __restrict__ in, uint4* __restrict__ out, int nvec) {
    int i = blockIdx.x * blockDim.x + threadIdx.x;
    if (i >= nvec) return;
    float4 a = in[2 * i], b = in[2 * i + 1];
    union { unsigned short s[8]; uint4 v; } o;
    o.s[0] = f2bf(a.x); o.s[1] = f2bf(a.y); o.s[2] = f2bf(a.z); o.s[3] = f2bf(a.w);
    o.s[4] = f2bf(b.x); o.s[5] = f2bf(b.y); o.s[6] = f2bf(b.z); o.s[7] = f2bf(b.w);
    out[i] = o.v;
}

// int8 values harness-materialized as int32; exact in bf16
__global__ void cvt_i32_bf16_k(const int4* __restrict__ in, uint4* __restrict__ out, int nvec) {
    int i = blockIdx.x * blockDim.x + threadIdx.x;
    if (i >= nvec) return;
    int4 a = in[2 * i], b = in[2 * i + 1];
    union { unsigned short s[8]; uint4 v; } o;
    o.s[0] = f2bf((float)a.x); o.s[1] = f2bf((float)a.y);
    o.s[2] = f2bf((float)a.z); o.s[3] = f2bf((float)a.w);
    o.s[4] = f2bf((float)b.x); o.s[5] = f2bf((float)b.y);
    o.s[6] = f2bf((float)b.z); o.s[7] = f2bf((float)b.w);
    out[i] = o.v;
}

// ---------------- m201-template 256x256 8-phase GEMM, BK=64, 2 K-tiles/iter ----------------
// 8 waves (2Mx4N), contiguous ownership: wave wm owns rows wm*128, wn owns cols wn*64.
// LDS 128KB: buf b at b*64KB {A: 2 halves [128][128B] at 0/16K; B same at 32K/48K}.
// Per iter: 8 phases, each {ds_reads; stage ONE 16KB half (2 gload_lds/thread); [wait]; barrier;
// setprio1; 16 MFMA (one quadrant x K=64); setprio0}. Quadrants: (m0n0)(m0n1)(m1n1)(m1n0);
// bn0 retained P0->P3, bn1 P1->P2, A requadrant-loaded P0/P2 (12/4/8/0 read balance).
// Stage schedule: P0:A0(t1)->buf1, P1:A1(t1), P2:B0(t0+2)->buf0, P3:B1(t0+2), P4:A0(t0+2),
// P5:A1(t0+2), P6:B0(t1+2)->buf1, P7:B1(t1+2). Waits: vmcnt(4) ONLY at P3,P7 (T4; 2 halves
// stay in flight); tail iter: P3 drains vmcnt(0), P7 no wait. Ledger + WAR death-windows
// verified phase-by-phase (A halves die P2/P6, B halves die P1/P5; every stage >= 1 barrier
// after death; every read covered by {vmcnt -> barrier}).
// Swizzle (proven 0-conflict, rounds 4-6): read slot (ks*4+cgi)^(l16&7), inverse on stage src.
// EPI==0: bf16 gelu(acc*sc+bi); EPI==1: f32 acc*sc+bi. Output row-stride hardcoded 4096.
template<int EPI>
__global__ __launch_bounds__(512, 2)
void gemm8q(const unsigned short* __restrict__ A, const unsigned short* __restrict__ B,
            const float* __restrict__ scale, const float* __restrict__ bias,
            void* __restrict__ Cout, int K) {
    extern __shared__ __align__(16) char sm[];   // 131072 bytes dynamic

    const int tid  = threadIdx.x;
    const int lane = tid & 63;
    const int wid  = tid >> 6;
    const int wm   = wid >> 2, wn = wid & 3;

    // T1: bijective XCD swizzle (m204)
    const int nwg  = gridDim.x;
    const int q    = nwg >> 3, r = nwg & 7;
    const int xcd  = blockIdx.x & 7, bidx = blockIdx.x >> 3;
    const int swz  = xcd * q + (xcd < r ? xcd : r) + bidx;
    const int tm   = swz / NTN, tn = swz % NTN;

    const size_t rowbytes = (size_t)K * 2;
    const char* Ag = (const char*)A + (size_t)tm * 256 * rowbytes;
    const char* Bg = (const char*)B + (size_t)tn * 256 * rowbytes;

    const int l16 = lane & 15;
    const int cgi = lane >> 4;
    const int sw  = l16 & 7;
    const int c0  = ((cgi       ^ sw) << 4);   // swizzled byte-slot, k-step 0
    const int c1  = (((4 | cgi) ^ sw) << 4);   // swizzled byte-slot, k-step 1

    f32x4  acc[8][4] = {};
    bf16x8 aq[4][2], bn0[2][2], bn1[2][2];

    const int NIT = K >> 7;   // iterations (2 K-tiles of 64 each)

// stage one 16KB half: rows HR..HR+127 of the 256-row tile, K-tile TILE, LDS offset LDSOFF.
// LDS dest linear; global source pre-inverse-swizzled (rule 21).
#define STAGE(GB, LDSOFF, HR, TILE) { \
    _Pragma("unroll") for (int ld_ = 0; ld_ < 2; ++ld_) { \
        const int po_ = (ld_ << 13) + (tid << 4); \
        const int pr_ = po_ >> 7; \
        const int pc_ = (po_ & 127) ^ ((pr_ & 7) << 4); \
        __builtin_amdgcn_global_load_lds( \
            (gchar*)((GB) + (size_t)((HR) + pr_) * rowbytes + ((size_t)(TILE) << 7) + (size_t)pc_), \
            (lchar*)(sm + (LDSOFF) + po_), 16, 0, 0); \
    } }

#define READ_A(BUFOFF, MH) { const char* Ab_ = sm + (BUFOFF) + wm * 16384; \
    _Pragma("unroll") for (int mm_ = 0; mm_ < 4; ++mm_) { \
        const int ro_ = (((MH) * 64) + mm_ * 16 + l16) << 7; \
        aq[mm_][0] = *(const bf16x8*)(Ab_ + ro_ + c0); \
        aq[mm_][1] = *(const bf16x8*)(Ab_ + ro_ + c1); } }

#define READ_B(BUFOFF, NH, DST) { const char* Bb_ = sm + (BUFOFF) + 32768 + (wn >> 1) * 16384; \
    _Pragma("unroll") for (int nn_ = 0; nn_ < 2; ++nn_) { \
        const int ro_ = (((wn & 1) * 64) + (NH) * 32 + nn_ * 16 + l16) << 7; \
        DST[nn_][0] = *(const bf16x8*)(Bb_ + ro_ + c0); \
        DST[nn_][1] = *(const bf16x8*)(Bb_ + ro_ + c1); } }

#define MF(MH, NH, BQ) { __builtin_amdgcn_s_setprio(1); \
    _Pragma("unroll") for (int mm_ = 0; mm_ < 4; ++mm_) \
        _Pragma("unroll") for (int nn_ = 0; nn_ < 2; ++nn_) { \
            acc[(MH)*4+mm_][(NH)*2+nn_] = MFMA16(aq[mm_][0], BQ[nn_][0], acc[(MH)*4+mm_][(NH)*2+nn_]); \
            acc[(MH)*4+mm_][(NH)*2+nn_] = MFMA16(aq[mm_][1], BQ[nn_][1], acc[(MH)*4+mm_][(NH)*2+nn_]); } \
    __builtin_amdgcn_s_setprio(0); }

#define SFENCE __builtin_amdgcn_sched_barrier(0)
#define WAITV4 { SFENCE; asm volatile("s_waitcnt vmcnt(4)"); SFENCE; }
#define WAITV0 { SFENCE; asm volatile("s_waitcnt vmcnt(0)"); SFENCE; }
#define BARR   { SFENCE; __builtin_amdgcn_s_barrier(); SFENCE; }

    // prologue: tile0 -> buf0 (4 halves), B(tile1) -> buf1 (2 halves). A(tile1) staged at j=0 P0/P1.
    STAGE(Ag, 0,             0,   0); STAGE(Ag, 16384,         128, 0);
    STAGE(Bg, 32768,         0,   0); STAGE(Bg, 49152,         128, 0);
    STAGE(Bg, 65536 + 32768, 0,   1); STAGE(Bg, 65536 + 49152, 128, 1);
    WAITV4; BARR;   // tile0's 8 loads landed; B(1)'s 4 still fly

    const int NT = K >> 6;
    for (int j = 0; j < NIT; ++j) {
        const int  t0 = 2 * j, t1 = 2 * j + 1;
        const bool p2 = (t0 + 2 < NT);
        const bool p3 = (t1 + 2 < NT);
        const bool lastj = (j == NIT - 1);

        // P0: quadrant (m0,n0) of tile t0 (buf0)
        READ_A(0, 0); READ_B(0, 0, bn0);
        STAGE(Ag, 65536, 0, t1);                       // A0(t1) -> buf1
        BARR; MF(0, 0, bn0);
        // P1: (m0,n1)
        READ_B(0, 1, bn1);
        STAGE(Ag, 65536 + 16384, 128, t1);             // A1(t1) -> buf1
        BARR; MF(0, 1, bn1);
        // P2: (m1,n1)
        READ_A(0, 1);
        if (p2) STAGE(Bg, 32768, 0, t0 + 2);           // B0(t0+2) -> buf0
        BARR; MF(1, 1, bn1);
        // P3: (m1,n0) — counted wait #1
        if (p2) STAGE(Bg, 49152, 128, t0 + 2);         // B1(t0+2) -> buf0
        if (lastj) { WAITV0; } else { WAITV4; }        // lands A(t1)+B(t1) for P4..P7
        BARR; MF(1, 0, bn0);
        // P4: (m0,n0) of tile t1 (buf1)
        READ_A(65536, 0); READ_B(65536, 0, bn0);
        if (p2) STAGE(Ag, 0, 0, t0 + 2);               // A0(t0+2) -> buf0
        BARR; MF(0, 0, bn0);
        // P5: (m0,n1)
        READ_B(65536, 1, bn1);
        if (p2) STAGE(Ag, 16384, 128, t0 + 2);         // A1(t0+2) -> buf0
        BARR; MF(0, 1, bn1);
        // P6: (m1,n1)
        READ_A(65536, 1);
        if (p3) STAGE(Bg, 65536 + 32768, 0, t1 + 2);   // B0(t1+2) -> buf1
        BARR; MF(1, 1, bn1);
        // P7: (m1,n0) — counted wait #2
        if (p3) STAGE(Bg, 65536 + 49152, 128, t1 + 2); // B1(t1+2) -> buf1
        if (!lastj) { WAITV4; }                        // lands tile t0+2 for next P0..P3
        BARR; MF(1, 0, bn0);
    }
#undef STAGE
#undef READ_A
#undef READ_B
#undef MF
#undef SFENCE
#undef WAITV4
#undef WAITV0
#undef BARR

    // epilogue: C/D frag layout col=lane&15, row=(lane>>4)*4+r  [m89/m91]
    const int rg = (lane >> 4) << 2;
    #pragma unroll
    for (int nq = 0; nq < 4; ++nq) {
        const int col = tn * 256 + wn * 64 + (nq >> 1) * 32 + (nq & 1) * 16 + l16;
        const float sc = scale[col];
        const float bi = bias[col];
        #pragma unroll
        for (int mq = 0; mq < 8; ++mq) {
            const int row0 = tm * 256 + wm * 128 + (mq >> 2) * 64 + (mq & 3) * 16 + rg;
            #pragma unroll
            for (int rr = 0; rr < 4; ++rr) {
                float v = acc[mq][nq][rr] * sc + bi;
                if (EPI == 0) {
                    float g = 0.5f * v * (1.0f + erff(v * 0.70710678118654752f));
                    ((unsigned short*)Cout)[(size_t)(row0 + rr) * 4096 + col] = f2bf(g);
                } else {
                    ((float*)Cout)[(size_t)(row0 + rr) * 4096 + col] = v;
                }
            }
        }
    }
}

extern "C" void kernel_launch(void* const* d_in, const int* in_sizes, int n_in,
                              void* d_out, int out_size, void* d_ws, size_t ws_size,
                              hipStream_t stream) {
    const float* x   = (const float*)d_in[0];
    const int*   w1q = (const int*)d_in[1];
    const float* s1  = (const float*)d_in[2];
    const float* b1  = (const float*)d_in[3];
    const int*   w2q = (const int*)d_in[4];
    const float* s2  = (const float*)d_in[5];
    const float* b2  = (const float*)d_in[6];
    float*       out = (float*)d_out;

    // allow 128 KiB dynamic LDS (idempotent, not a stream op)
    hipFuncSetAttribute((const void*)gemm8q<0>, hipFuncAttributeMaxDynamicSharedMemorySize, 131072);
    hipFuncSetAttribute((const void*)gemm8q<1>, hipFuncAttributeMaxDynamicSharedMemorySize, 131072);

    char* ws = (char*)d_ws;
    const size_t XBF  = (size_t)NROWS   * IN_DIM  * 2;
    const size_t W1BF = (size_t)HID_DIM * IN_DIM  * 2;
    const size_t W2BF = (size_t)OUT_DIM * HID_DIM * 2;
    const size_t FIXED = XBF + W1BF + W2BF;

    unsigned short* xbf  = (unsigned short*)ws;
    unsigned short* w1bf = (unsigned short*)(ws + XBF);
    unsigned short* w2bf = (unsigned short*)(ws + XBF + W1BF);
    unsigned short* hbuf = (unsigned short*)(ws + FIXED);

    {
        int nvx = NROWS * IN_DIM / 8;
        cvt_f32_bf16_k<<<(nvx + 255) / 256, 256, 0, stream>>>((const float4*)x, (uint4*)xbf, nvx);
        int nv1 = HID_DIM * IN_DIM / 8;
        cvt_i32_bf16_k<<<(nv1 + 255) / 256, 256, 0, stream>>>((const int4*)w1q, (uint4*)w1bf, nv1);
        int nv2 = OUT_DIM * HID_DIM / 8;
        cvt_i32_bf16_k<<<(nv2 + 255) / 256, 256, 0, stream>>>((const int4*)w2q, (uint4*)w2bf, nv2);
    }

    // chunk M (multiples of 256) so h fits in remaining workspace
    size_t avail = (ws_size > FIXED) ? (ws_size - FIXED) : 0;
    long rp = (long)(avail / ((size_t)HID_DIM * 2));
    rp = (rp / 256) * 256;
    if (rp > NROWS) rp = NROWS;
    if (rp < 256)   rp = 256;

    for (int r0 = 0; r0 < NROWS; r0 += (int)rp) {
        int rows = (int)(((long)(NROWS - r0) < rp) ? (NROWS - r0) : rp);
        dim3 g(NTN * (rows / 256));
        gemm8q<0><<<g, 512, 131072, stream>>>(xbf + (size_t)r0 * IN_DIM, w1bf, s1, b1,
                                              (void*)hbuf, IN_DIM);
        gemm8q<1><<<g, 512, 131072, stream>>>(hbuf, w2bf, s2, b2,
                                              (void*)(out + (size_t)r0 * OUT_DIM), HID_DIM);
    }
    (void)in_sizes; (void)n_in; (void)out_size;
}